// Round 3
// baseline (6042.724 us; speedup 1.0000x reference)
//
#include <hip/hip_runtime.h>
#include <hip/hip_bf16.h>
#include <stdint.h>
#include <stddef.h>

#define SEQ   512
#define BATCH 64
#define NIN   1024
#define NHID  1024
#define NG    4096   // 4*NHID

typedef __attribute__((ext_vector_type(8))) short bf16x8;
typedef __attribute__((ext_vector_type(4))) float f32x4;

static __device__ __forceinline__ ushort f2bf(float f) {
  uint32_t u = __builtin_bit_cast(uint32_t, f);
  uint32_t lsb = (u >> 16) & 1u;
  u += 0x7fffu + lsb;           // round-to-nearest-even
  return (ushort)(u >> 16);
}

static __device__ __forceinline__ f32x4 mfma_bf16(bf16x8 a, bf16x8 b, f32x4 c) {
  return __builtin_amdgcn_mfma_f32_16x16x32_bf16(a, b, c, 0, 0, 0);
}

static __device__ __forceinline__ void lds_load16(const ushort* g, ushort* l) {
  __builtin_amdgcn_global_load_lds(
      (const __attribute__((address_space(1))) void*)g,
      (__attribute__((address_space(3))) void*)l, 16, 0, 0);
}

// ---------------- converts ----------------

__global__ __launch_bounds__(256) void k_convert_x(const float* __restrict__ X,
                                                   ushort* __restrict__ Xb, int n4) {
  int i = blockIdx.x * 256 + threadIdx.x;
  if (i < n4) {
    float4 v = ((const float4*)X)[i];
    ushort4 o;
    o.x = f2bf(v.x); o.y = f2bf(v.y); o.z = f2bf(v.z); o.w = f2bf(v.w);
    ((ushort4*)Xb)[i] = o;
  }
}

// permuted row order: p = cg*64 + g*16 + j  <->  r = g*1024 + cg*16 + j
__global__ __launch_bounds__(256) void k_convert_w(const float* __restrict__ W,
                                                   const float* __restrict__ bvec,
                                                   ushort* __restrict__ Wxb,
                                                   ushort* __restrict__ Whb,
                                                   float* __restrict__ bp) {
  int p = blockIdx.x;
  int cg = p >> 6, g = (p >> 4) & 3, j = p & 15;
  int r = g * 1024 + cg * 16 + j;
  const float* src = W + (size_t)r * 2048;
  for (int k4 = threadIdx.x; k4 < 512; k4 += 256) {
    float4 v = ((const float4*)src)[k4];
    ushort4 o;
    o.x = f2bf(v.x); o.y = f2bf(v.y); o.z = f2bf(v.z); o.w = f2bf(v.w);
    if (k4 < 256) ((ushort4*)(Wxb + (size_t)p * 1024))[k4] = o;
    else          ((ushort4*)(Whb + (size_t)p * 1024))[k4 - 256] = o;
  }
  if (threadIdx.x == 0) bp[p] = bvec[r];
}

__global__ __launch_bounds__(256) void k_zero(ushort* __restrict__ hb0,
                                              ushort* __restrict__ hb1,
                                              float* __restrict__ cst,
                                              uint32_t* __restrict__ flags) {
  int i = blockIdx.x * 256 + threadIdx.x;  // 65536 total
  hb0[i] = 0; hb1[i] = 0; cst[i] = 0.f;
  if (blockIdx.x == 0) flags[threadIdx.x] = 0;
}

// ---------------- GEMM1: Ax[m][p] = sum_k Xb[m][k]*Wxb[p][k] + bp[p] ----------------
// 128x128 tile, BK=32, 4 waves (2x2 of 64x64)

__global__ __launch_bounds__(256) void k_gemm1(const ushort* __restrict__ Xb,
                                               const ushort* __restrict__ Wxb,
                                               const float* __restrict__ bp,
                                               float* __restrict__ Ax) {
  __shared__ ushort As[128 * 32];
  __shared__ ushort Bs[128 * 32];
  const int m0 = blockIdx.x * 128;
  const int n0 = blockIdx.y * 128;
  const int tid = threadIdx.x;
  const int w = tid >> 6, l = tid & 63;
  const int wr = w >> 1, wc = w & 1;
  const int lr = l >> 2;          // row within 16-row chunk
  const int lc = (l & 3) * 8;     // elem col within 32
  const int fr = l & 15, fk8 = (l >> 4) * 8, fq = l >> 4;

  f32x4 acc[4][4] = {};

  for (int kb = 0; kb < 1024; kb += 32) {
    lds_load16(Xb  + (size_t)(m0 + w * 16 + lr) * 1024 + kb + lc,       &As[w * 512]);
    lds_load16(Xb  + (size_t)(m0 + (w + 4) * 16 + lr) * 1024 + kb + lc, &As[(w + 4) * 512]);
    lds_load16(Wxb + (size_t)(n0 + w * 16 + lr) * 1024 + kb + lc,       &Bs[w * 512]);
    lds_load16(Wxb + (size_t)(n0 + (w + 4) * 16 + lr) * 1024 + kb + lc, &Bs[(w + 4) * 512]);
    __syncthreads();
    bf16x8 af[4], bfr[4];
#pragma unroll
    for (int i = 0; i < 4; i++) af[i]  = *(const bf16x8*)&As[(wr * 64 + i * 16 + fr) * 32 + fk8];
#pragma unroll
    for (int i = 0; i < 4; i++) bfr[i] = *(const bf16x8*)&Bs[(wc * 64 + i * 16 + fr) * 32 + fk8];
#pragma unroll
    for (int i = 0; i < 4; i++)
#pragma unroll
      for (int jj = 0; jj < 4; jj++)
        acc[i][jj] = mfma_bf16(af[i], bfr[jj], acc[i][jj]);
    __syncthreads();
  }

#pragma unroll
  for (int jj = 0; jj < 4; jj++) {
    int gc = n0 + wc * 64 + jj * 16 + fr;
    float bb = bp[gc];
#pragma unroll
    for (int i = 0; i < 4; i++) {
      int grb = m0 + wr * 64 + i * 16 + fq * 4;
#pragma unroll
      for (int jr = 0; jr < 4; jr++)
        Ax[(size_t)(grb + jr) * NG + gc] = acc[i][jj][jr] + bb;
    }
  }
}

// ---------------- persistent recurrence (plain launch, 1 block/CU) ----------------
// grid 256 = 4 teams x 64 hidden-groups. 144KB LDS/block -> exactly 1 block/CU,
// grid == CU count -> all blocks co-resident (no coop launch needed; coop is not
// graph-capturable). Team t owns batches [t*16,+16). Block hg owns h-cols
// [hg*16,+16) = permuted gate cols [hg*64,+64). Wh slice (64x1024 bf16 = 128KB)
// LDS-resident, XOR-swizzled. c-state in registers. Team barrier: monotonic
// per-block epoch flags, agent-scope atomics + fences (Guideline 16).

__global__ __launch_bounds__(256) void k_persist(const ushort* __restrict__ Whb,
                                                 const float* __restrict__ Ax,
                                                 ushort* __restrict__ hb0,
                                                 ushort* __restrict__ hb1,
                                                 float* __restrict__ out,
                                                 uint32_t* __restrict__ flags) {
  __shared__ ushort Wsh[64 * 1024];      // 128 KB
  __shared__ float red[4][16][64];       // 16 KB

  const int bid = blockIdx.x;
  const int team = bid >> 6, hg = bid & 63;
  const int tid = threadIdx.x, w = tid >> 6, l = tid & 63;
  const int fr = l & 15, fq = l >> 4, fk8 = fq * 8;
  const int xm = (fr & 7) << 3;          // per-lane LDS XOR mask (elem units)

  // ---- stage Wh slice into LDS (once), swizzled ----
  {
    const ushort* wsrc = Whb + (size_t)(hg * 64) * 1024;
    for (int it = 0; it < 32; ++it) {
      int idx = it * 256 + tid;          // 8192 chunks of 8 elems
      int row = idx >> 7, c8 = idx & 127;
      bf16x8 v = *(const bf16x8*)(wsrc + (size_t)row * 1024 + c8 * 8);
      int col = (c8 * 8) ^ ((row & 7) << 3);
      *(bf16x8*)&Wsh[row * 1024 + col] = v;
    }
  }
  __syncthreads();

  const int eb = tid >> 4, ej = tid & 15;  // epilogue: batch-in-team, hcol-in-group
  float creg = 0.f;

  uint32_t* myflag = flags + bid;
  uint32_t* tflags = flags + team * 64;

  for (int t = 0; t < SEQ; ++t) {
    const ushort* hb_r = (t & 1) ? hb1 : hb0;
    ushort*       hb_w = (t & 1) ? hb0 : hb1;

    // ---- prefetch Ax[t] (h-independent) so latency hides under the spin ----
    const float* axp = Ax + ((size_t)t * 64 + team * 16 + eb) * NG + hg * 64;
    float ax0 = axp[ej], ax1 = axp[16 + ej], ax2 = axp[32 + ej], ax3 = axp[48 + ej];

    if (t > 0) {
      if (w == 0) {
        while (true) {
          uint32_t v = __hip_atomic_load(&tflags[l], __ATOMIC_RELAXED,
                                         __HIP_MEMORY_SCOPE_AGENT);
          if (__all((int)(v >= (uint32_t)t))) break;
          __builtin_amdgcn_s_sleep(1);
        }
        __threadfence();  // acquire: invalidate stale caches before h reads
      }
      __syncthreads();
    }

    // ---- MFMA: gates[16b x 64p] over K=1024, split 4 ways across waves ----
    const ushort* aSrc = hb_r + (size_t)(team * 16 + fr) * 1024 + w * 256 + fk8;
    f32x4 acc[4] = {};
#pragma unroll
    for (int ks = 0; ks < 8; ++ks) {
      bf16x8 a = *(const bf16x8*)(aSrc + ks * 32);
#pragma unroll
      for (int bj = 0; bj < 4; ++bj) {
        int row = bj * 16 + fr;
        int col = (w * 256 + ks * 32 + fk8) ^ xm;
        bf16x8 bv = *(const bf16x8*)&Wsh[row * 1024 + col];
        acc[bj] = mfma_bf16(a, bv, acc[bj]);
      }
    }

#pragma unroll
    for (int bj = 0; bj < 4; ++bj)
#pragma unroll
      for (int jr = 0; jr < 4; ++jr)
        red[w][fq * 4 + jr][bj * 16 + fr] = acc[bj][jr];
    __syncthreads();

    // ---- epilogue: one (batch, hcol) per thread ----
    float ai_ = 0.f, af_ = 0.f, ao_ = 0.f, ag_ = 0.f;
#pragma unroll
    for (int ww = 0; ww < 4; ++ww) {
      ai_ += red[ww][eb][ej];
      af_ += red[ww][eb][16 + ej];
      ao_ += red[ww][eb][32 + ej];
      ag_ += red[ww][eb][48 + ej];
    }
    ai_ += ax0; af_ += ax1; ao_ += ax2; ag_ += ax3;

    float ig = 1.f / (1.f + __expf(-ai_));
    float fg = 1.f / (1.f + __expf(-af_));
    float og = 1.f / (1.f + __expf(-ao_));
    float gg = tanhf(ag_);
    creg = creg * fg + ig * gg;
    float h = og * tanhf(creg);
    int hidx = (team * 16 + eb) * 1024 + hg * 16 + ej;
    out[(size_t)t * 65536 + hidx] = h;
    hb_w[hidx] = f2bf(h);
    if (t == SEQ - 1) out[(size_t)SEQ * 65536 + hidx] = h;

    // ---- publish: block stores drained by syncthreads, then fence+flag ----
    __syncthreads();
    if (tid == 0) {
      __threadfence();  // release: make h stores agent-visible
      __hip_atomic_store(myflag, (uint32_t)(t + 1), __ATOMIC_RELAXED,
                         __HIP_MEMORY_SCOPE_AGENT);
    }
  }
}

// ---------------- fallback per-step kernel (ws too small for Ax) ----------------

template <int MODE>
__global__ __launch_bounds__(256) void k_step(int t,
                                              const ushort* __restrict__ Xb,
                                              const ushort* __restrict__ Wxb,
                                              const ushort* __restrict__ Whb,
                                              const float* __restrict__ bp,
                                              const float* __restrict__ Ax,
                                              const ushort* __restrict__ hprev,
                                              ushort* __restrict__ hnext,
                                              float* __restrict__ cst,
                                              float* __restrict__ out) {
  __shared__ float red[4][16][64];
  const int bidx = blockIdx.x;
  const int cg = bidx & 63, mb = bidx >> 6;
  const int b0 = mb * 16, pcol = cg * 64;
  const int tid = threadIdx.x, w = tid >> 6, l = tid & 63;
  const int fr = l & 15, fk8 = (l >> 4) * 8, fq = l >> 4;

  f32x4 acc[4] = {};

  const ushort* aSrc;
  const ushort* bMat;
  int kbase;
  if (MODE == 0) {
    aSrc = hprev + (size_t)(b0 + fr) * 1024 + w * 256 + fk8;
    bMat = Whb; kbase = w * 256;
  } else {
    if (w < 2) { aSrc = Xb + (size_t)(t * 64 + b0 + fr) * 1024 + w * 512 + fk8; bMat = Wxb; kbase = w * 512; }
    else       { aSrc = hprev + (size_t)(b0 + fr) * 1024 + (w - 2) * 512 + fk8; bMat = Whb; kbase = (w - 2) * 512; }
  }
  const ushort* bRow = bMat + (size_t)(pcol + fr) * 1024 + kbase + fk8;

#pragma unroll
  for (int ks = 0; ks < ((MODE == 0) ? 8 : 16); ks++) {
    int kk = ks * 32;
    bf16x8 a = *(const bf16x8*)(aSrc + kk);
#pragma unroll
    for (int bj = 0; bj < 4; bj++) {
      bf16x8 bfv = *(const bf16x8*)(bRow + (size_t)bj * 16 * 1024 + kk);
      acc[bj] = mfma_bf16(a, bfv, acc[bj]);
    }
  }

#pragma unroll
  for (int bj = 0; bj < 4; bj++)
#pragma unroll
    for (int jr = 0; jr < 4; jr++)
      red[w][fq * 4 + jr][bj * 16 + fr] = acc[bj][jr];
  __syncthreads();

  const int b = tid >> 4, j = tid & 15;
  float ai_ = 0.f, af_ = 0.f, ao_ = 0.f, ag_ = 0.f;
#pragma unroll
  for (int ww = 0; ww < 4; ww++) {
    ai_ += red[ww][b][j];
    af_ += red[ww][b][16 + j];
    ao_ += red[ww][b][32 + j];
    ag_ += red[ww][b][48 + j];
  }
  if (MODE == 0) {
    const float* axp = Ax + (size_t)(t * 64 + b0 + b) * NG + pcol;
    ai_ += axp[j]; af_ += axp[16 + j]; ao_ += axp[32 + j]; ag_ += axp[48 + j];
  } else {
    ai_ += bp[pcol + j]; af_ += bp[pcol + 16 + j]; ao_ += bp[pcol + 32 + j]; ag_ += bp[pcol + 48 + j];
  }
  float ig = 1.f / (1.f + __expf(-ai_));
  float fg = 1.f / (1.f + __expf(-af_));
  float og = 1.f / (1.f + __expf(-ao_));
  float gg = tanhf(ag_);
  int hidx = (b0 + b) * 1024 + cg * 16 + j;
  float cn = cst[hidx] * fg + ig * gg;
  cst[hidx] = cn;
  float h = og * tanhf(cn);
  out[(size_t)t * 65536 + hidx] = h;
  hnext[hidx] = f2bf(h);
  if (t == SEQ - 1) out[(size_t)SEQ * 65536 + hidx] = h;
}

// ---------------- host ----------------

extern "C" void kernel_launch(void* const* d_in, const int* in_sizes, int n_in,
                              void* d_out, int out_size, void* d_ws, size_t ws_size,
                              hipStream_t stream) {
  const float* X    = (const float*)d_in[0];
  const float* W    = (const float*)d_in[1];
  const float* bvec = (const float*)d_in[2];
  float* out = (float*)d_out;
  char* ws = (char*)d_ws;

  size_t off = 0;
  auto alloc = [&](size_t bytes) -> char* {
    char* p = ws + off;
    off += (bytes + 255) & ~(size_t)255;
    return p;
  };
  ushort* Xb    = (ushort*)alloc((size_t)SEQ * BATCH * NIN * 2);
  ushort* Wxb   = (ushort*)alloc((size_t)NG * NIN * 2);
  ushort* Whb   = (ushort*)alloc((size_t)NG * NHID * 2);
  float*  bp    = (float*)alloc((size_t)NG * 4);
  ushort* hb0   = (ushort*)alloc((size_t)BATCH * NHID * 2);
  ushort* hb1   = (ushort*)alloc((size_t)BATCH * NHID * 2);
  float*  cst   = (float*)alloc((size_t)BATCH * NHID * 4);
  uint32_t* flg = (uint32_t*)alloc(256 * 4);
  size_t base_need = off;
  float*  Ax  = (float*)alloc((size_t)SEQ * BATCH * NG * 4);
  size_t fast_need = off;

  if (ws_size < base_need) return;
  const bool fast = (ws_size >= fast_need);

  k_convert_x<<<(SEQ * BATCH * NIN / 4 + 255) / 256, 256, 0, stream>>>(X, Xb, SEQ * BATCH * NIN / 4);
  k_convert_w<<<NG, 256, 0, stream>>>(W, bvec, Wxb, Whb, bp);
  k_zero<<<BATCH * NHID / 256, 256, 0, stream>>>(hb0, hb1, cst, flg);

  if (fast) {
    k_gemm1<<<dim3(SEQ * BATCH / 128, NG / 128), 256, 0, stream>>>(Xb, Wxb, bp, Ax);
    // Plain (graph-capturable) launch. 144KB LDS -> 1 block/CU; grid 256 == #CUs
    // -> all teams co-resident.
    k_persist<<<256, 256, 0, stream>>>(Whb, Ax, hb0, hb1, out, flg);
  } else {
    for (int t = 0; t < SEQ; t++) {
      const ushort* hp = (t & 1) ? hb1 : hb0;
      ushort*       hn = (t & 1) ? hb0 : hb1;
      k_step<1><<<256, 256, 0, stream>>>(t, Xb, Wxb, Whb, bp, Ax, hp, hn, cst, out);
    }
  }
}

// Round 4
// 3112.113 us; speedup vs baseline: 1.9417x; 1.9417x over previous
//
#include <hip/hip_runtime.h>
#include <hip/hip_bf16.h>
#include <stdint.h>
#include <stddef.h>

#define SEQ   512
#define BATCH 64
#define NIN   1024
#define NHID  1024
#define NG    4096   // 4*NHID

typedef __attribute__((ext_vector_type(8))) short bf16x8;
typedef __attribute__((ext_vector_type(4))) float f32x4;
typedef __attribute__((ext_vector_type(4))) uint32_t u32x4;

static __device__ __forceinline__ ushort f2bf(float f) {
  uint32_t u = __builtin_bit_cast(uint32_t, f);
  uint32_t lsb = (u >> 16) & 1u;
  u += 0x7fffu + lsb;           // round-to-nearest-even
  return (ushort)(u >> 16);
}

static __device__ __forceinline__ f32x4 mfma_bf16(bf16x8 a, bf16x8 b, f32x4 c) {
  return __builtin_amdgcn_mfma_f32_16x16x32_bf16(a, b, c, 0, 0, 0);
}

static __device__ __forceinline__ void lds_load16(const ushort* g, ushort* l) {
  __builtin_amdgcn_global_load_lds(
      (const __attribute__((address_space(1))) void*)g,
      (__attribute__((address_space(3))) void*)l, 16, 0, 0);
}

// L3-coherent (cross-XCD) primitives: sc0 sc1 bypasses L1+L2 both ways.
static __device__ __forceinline__ void st_short_l3(ushort* p, uint32_t v) {
  asm volatile("global_store_short %0, %1, off sc0 sc1" :: "v"(p), "v"(v) : "memory");
}
static __device__ __forceinline__ void st_dword_l3(uint32_t* p, uint32_t v) {
  asm volatile("global_store_dword %0, %1, off sc0 sc1" :: "v"(p), "v"(v) : "memory");
}
static __device__ __forceinline__ uint32_t ld_dword_l3(const uint32_t* p) {
  uint32_t v;
  asm volatile("global_load_dword %0, %1, off sc0 sc1\n\ts_waitcnt vmcnt(0)"
               : "=v"(v) : "v"(p) : "memory");
  return v;
}

// ---------------- converts ----------------

__global__ __launch_bounds__(256) void k_convert_x(const float* __restrict__ X,
                                                   ushort* __restrict__ Xb, int n4) {
  int i = blockIdx.x * 256 + threadIdx.x;
  if (i < n4) {
    float4 v = ((const float4*)X)[i];
    ushort4 o;
    o.x = f2bf(v.x); o.y = f2bf(v.y); o.z = f2bf(v.z); o.w = f2bf(v.w);
    ((ushort4*)Xb)[i] = o;
  }
}

// permuted row order: p = cg*64 + g*16 + j  <->  r = g*1024 + cg*16 + j
__global__ __launch_bounds__(256) void k_convert_w(const float* __restrict__ W,
                                                   const float* __restrict__ bvec,
                                                   ushort* __restrict__ Wxb,
                                                   ushort* __restrict__ Whb,
                                                   float* __restrict__ bp) {
  int p = blockIdx.x;
  int cg = p >> 6, g = (p >> 4) & 3, j = p & 15;
  int r = g * 1024 + cg * 16 + j;
  const float* src = W + (size_t)r * 2048;
  for (int k4 = threadIdx.x; k4 < 512; k4 += 256) {
    float4 v = ((const float4*)src)[k4];
    ushort4 o;
    o.x = f2bf(v.x); o.y = f2bf(v.y); o.z = f2bf(v.z); o.w = f2bf(v.w);
    if (k4 < 256) ((ushort4*)(Wxb + (size_t)p * 1024))[k4] = o;
    else          ((ushort4*)(Whb + (size_t)p * 1024))[k4 - 256] = o;
  }
  if (threadIdx.x == 0) bp[p] = bvec[r];
}

// zero h ping-pong (through L3 so sc-bypassing readers see it), c-state, flags
__global__ __launch_bounds__(256) void k_zero(ushort* __restrict__ hb0,
                                              ushort* __restrict__ hb1,
                                              float* __restrict__ cst,
                                              uint32_t* __restrict__ flags) {
  int i = blockIdx.x * 256 + threadIdx.x;  // 65536 total
  st_short_l3(hb0 + i, 0u);
  st_short_l3(hb1 + i, 0u);
  cst[i] = 0.f;
  if (blockIdx.x == 0) st_dword_l3(flags + threadIdx.x, 0u);
}

// ---------------- GEMM1 chunk: Axc[m][p] = sum_k Xbc[m][k]*Wxb[p][k] + bp[p] ----------------
// 128x128 tile, BK=32, 4 waves (2x2 of 64x64). M = TC*64 rows of the Xb chunk.

__global__ __launch_bounds__(256) void k_gemm1(const ushort* __restrict__ Xbc,
                                               const ushort* __restrict__ Wxb,
                                               const float* __restrict__ bp,
                                               float* __restrict__ Axc) {
  __shared__ ushort As[128 * 32];
  __shared__ ushort Bs[128 * 32];
  const int m0 = blockIdx.x * 128;
  const int n0 = blockIdx.y * 128;
  const int tid = threadIdx.x;
  const int w = tid >> 6, l = tid & 63;
  const int wr = w >> 1, wc = w & 1;
  const int lr = l >> 2;          // row within 16-row chunk
  const int lc = (l & 3) * 8;     // elem col within 32
  const int fr = l & 15, fk8 = (l >> 4) * 8, fq = l >> 4;

  f32x4 acc[4][4] = {};

  for (int kb = 0; kb < 1024; kb += 32) {
    lds_load16(Xbc + (size_t)(m0 + w * 16 + lr) * 1024 + kb + lc,       &As[w * 512]);
    lds_load16(Xbc + (size_t)(m0 + (w + 4) * 16 + lr) * 1024 + kb + lc, &As[(w + 4) * 512]);
    lds_load16(Wxb + (size_t)(n0 + w * 16 + lr) * 1024 + kb + lc,       &Bs[w * 512]);
    lds_load16(Wxb + (size_t)(n0 + (w + 4) * 16 + lr) * 1024 + kb + lc, &Bs[(w + 4) * 512]);
    __syncthreads();
    bf16x8 af[4], bfr[4];
#pragma unroll
    for (int i = 0; i < 4; i++) af[i]  = *(const bf16x8*)&As[(wr * 64 + i * 16 + fr) * 32 + fk8];
#pragma unroll
    for (int i = 0; i < 4; i++) bfr[i] = *(const bf16x8*)&Bs[(wc * 64 + i * 16 + fr) * 32 + fk8];
#pragma unroll
    for (int i = 0; i < 4; i++)
#pragma unroll
      for (int jj = 0; jj < 4; jj++)
        acc[i][jj] = mfma_bf16(af[i], bfr[jj], acc[i][jj]);
    __syncthreads();
  }

#pragma unroll
  for (int jj = 0; jj < 4; jj++) {
    int gc = n0 + wc * 64 + jj * 16 + fr;
    float bb = bp[gc];
#pragma unroll
    for (int i = 0; i < 4; i++) {
      int grb = m0 + wr * 64 + i * 16 + fq * 4;
#pragma unroll
      for (int jr = 0; jr < 4; jr++)
        Axc[(size_t)(grb + jr) * NG + gc] = acc[i][jj][jr] + bb;
    }
  }
}

// ---------------- persistent recurrence chunk (plain launch, 1 block/CU) ----------------
// grid 256 = 4 teams x 64 hidden-groups. 144KB LDS/block -> 1 block/CU; grid ==
// #CUs -> co-resident. Team t owns batches [t*16,+16). Block hg owns h-cols
// [hg*16,+16) = permuted gate cols [hg*64,+64). Wh slice (64x1024 bf16 = 128KB)
// LDS-resident, XOR-swizzled. c-state in registers (spilled to cst at chunk
// boundaries). Cross-block h/flag exchange goes through L3 via sc0 sc1 ops --
// no cache-flush fences (works regardless of block->XCD placement, G16).

__global__ __launch_bounds__(256) void k_persist(const ushort* __restrict__ Whb,
                                                 const float* __restrict__ Axc,
                                                 ushort* __restrict__ hb0,
                                                 ushort* __restrict__ hb1,
                                                 float* __restrict__ out,
                                                 uint32_t* __restrict__ flags,
                                                 float* __restrict__ cst,
                                                 int t0, int TC) {
  __shared__ ushort Wsh[64 * 1024];      // 128 KB
  __shared__ float red[4][16][64];       // 16 KB

  const int bid = blockIdx.x;
  const int team = bid >> 6, hg = bid & 63;
  const int tid = threadIdx.x, w = tid >> 6, l = tid & 63;
  const int fr = l & 15, fq = l >> 4, fk8 = fq * 8;
  const int xm = (fr & 7) << 3;          // per-lane LDS XOR mask (elem units)

  // ---- stage Wh slice into LDS (once per chunk), swizzled ----
  {
    const ushort* wsrc = Whb + (size_t)(hg * 64) * 1024;
    for (int it = 0; it < 32; ++it) {
      int idx = it * 256 + tid;          // 8192 chunks of 8 elems
      int row = idx >> 7, c8 = idx & 127;
      bf16x8 v = *(const bf16x8*)(wsrc + (size_t)row * 1024 + c8 * 8);
      int col = (c8 * 8) ^ ((row & 7) << 3);
      *(bf16x8*)&Wsh[row * 1024 + col] = v;
    }
  }

  const int eb = tid >> 4, ej = tid & 15;  // epilogue: batch-in-team, hcol-in-group
  const int hidx_self = (team * 16 + eb) * 1024 + hg * 16 + ej;
  float creg = cst[hidx_self];
  __syncthreads();

  uint32_t* myflag = flags + bid;
  const uint32_t* tflags = flags + team * 64;

  for (int tt = 0; tt < TC; ++tt) {
    const int t = t0 + tt;
    const ushort* hb_r = (t & 1) ? hb1 : hb0;
    ushort*       hb_w = (t & 1) ? hb0 : hb1;

    // ---- prefetch Ax[t] (h-independent, cached) -- latency hides under spin ----
    const float* axp = Axc + ((size_t)tt * 64 + team * 16 + eb) * NG + hg * 64;
    float ax0 = axp[ej], ax1 = axp[16 + ej], ax2 = axp[32 + ej], ax3 = axp[48 + ej];

    if (t > 0) {
      if (w == 0) {
        int guard = 0;
        while (true) {
          uint32_t v = ld_dword_l3(tflags + l);
          if (__all((int)(v >= (uint32_t)t))) break;
          if (++guard > (1 << 15)) break;   // bug guard: fail, don't hang
          __builtin_amdgcn_s_sleep(1);
        }
      }
      __syncthreads();
    }

    // ---- h loads direct from L3 (writers stored sc0sc1) ----
    const ushort* aBase = hb_r + (size_t)(team * 16 + fr) * 1024 + w * 256 + fk8;
    u32x4 hv[8];
#pragma unroll
    for (int ks = 0; ks < 8; ++ks) {
      asm volatile("global_load_dwordx4 %0, %1, off sc0 sc1"
                   : "=v"(hv[ks]) : "v"(aBase + ks * 32) : "memory");
    }
    asm volatile("s_waitcnt vmcnt(0)" ::: "memory");
    __builtin_amdgcn_sched_barrier(0);

    // ---- MFMA: gates[16b x 64p] over K=1024, split 4 ways across waves ----
    f32x4 acc[4] = {};
#pragma unroll
    for (int ks = 0; ks < 8; ++ks) {
      bf16x8 a = __builtin_bit_cast(bf16x8, hv[ks]);
#pragma unroll
      for (int bj = 0; bj < 4; ++bj) {
        int row = bj * 16 + fr;
        int col = (w * 256 + ks * 32 + fk8) ^ xm;
        bf16x8 bv = *(const bf16x8*)&Wsh[row * 1024 + col];
        acc[bj] = mfma_bf16(a, bv, acc[bj]);
      }
    }

#pragma unroll
    for (int bj = 0; bj < 4; ++bj)
#pragma unroll
      for (int jr = 0; jr < 4; ++jr)
        red[w][fq * 4 + jr][bj * 16 + fr] = acc[bj][jr];
    __syncthreads();

    // ---- epilogue: one (batch, hcol) per thread ----
    float ai_ = 0.f, af_ = 0.f, ao_ = 0.f, ag_ = 0.f;
#pragma unroll
    for (int ww = 0; ww < 4; ++ww) {
      ai_ += red[ww][eb][ej];
      af_ += red[ww][eb][16 + ej];
      ao_ += red[ww][eb][32 + ej];
      ag_ += red[ww][eb][48 + ej];
    }
    ai_ += ax0; af_ += ax1; ao_ += ax2; ag_ += ax3;

    float ig = 1.f / (1.f + __expf(-ai_));
    float fg = 1.f / (1.f + __expf(-af_));
    float og = 1.f / (1.f + __expf(-ao_));
    float gg = tanhf(ag_);
    creg = creg * fg + ig * gg;
    float h = og * tanhf(creg);
    out[(size_t)t * 65536 + hidx_self] = h;
    st_short_l3(hb_w + hidx_self, (uint32_t)f2bf(h));
    if (t == SEQ - 1) out[(size_t)SEQ * 65536 + hidx_self] = h;

    // each thread drains its own h store to L3, then one flag per block
    asm volatile("s_waitcnt vmcnt(0)" ::: "memory");
    __syncthreads();
    if (tid == 0) st_dword_l3(myflag, (uint32_t)(t + 1));
  }

  cst[hidx_self] = creg;
}

// ---------------- fallback per-step kernel (ws too small for any Ax chunk) ----------------

__global__ __launch_bounds__(256) void k_step(int t,
                                              const ushort* __restrict__ Xb,
                                              const ushort* __restrict__ Wxb,
                                              const ushort* __restrict__ Whb,
                                              const float* __restrict__ bp,
                                              const ushort* __restrict__ hprev,
                                              ushort* __restrict__ hnext,
                                              float* __restrict__ cst,
                                              float* __restrict__ out) {
  __shared__ float red[4][16][64];
  const int bidx = blockIdx.x;
  const int cg = bidx & 63, mb = bidx >> 6;
  const int b0 = mb * 16, pcol = cg * 64;
  const int tid = threadIdx.x, w = tid >> 6, l = tid & 63;
  const int fr = l & 15, fk8 = (l >> 4) * 8, fq = l >> 4;

  f32x4 acc[4] = {};

  const ushort* aSrc;
  const ushort* bMat;
  int kbase;
  if (w < 2) { aSrc = Xb + (size_t)(t * 64 + b0 + fr) * 1024 + w * 512 + fk8; bMat = Wxb; kbase = w * 512; }
  else       { aSrc = hprev + (size_t)(b0 + fr) * 1024 + (w - 2) * 512 + fk8; bMat = Whb; kbase = (w - 2) * 512; }
  const ushort* bRow = bMat + (size_t)(pcol + fr) * 1024 + kbase + fk8;

#pragma unroll
  for (int ks = 0; ks < 16; ks++) {
    int kk = ks * 32;
    bf16x8 a = *(const bf16x8*)(aSrc + kk);
#pragma unroll
    for (int bj = 0; bj < 4; bj++) {
      bf16x8 bfv = *(const bf16x8*)(bRow + (size_t)bj * 16 * 1024 + kk);
      acc[bj] = mfma_bf16(a, bfv, acc[bj]);
    }
  }

#pragma unroll
  for (int bj = 0; bj < 4; bj++)
#pragma unroll
    for (int jr = 0; jr < 4; jr++)
      red[w][fq * 4 + jr][bj * 16 + fr] = acc[bj][jr];
  __syncthreads();

  const int b = tid >> 4, j = tid & 15;
  float ai_ = 0.f, af_ = 0.f, ao_ = 0.f, ag_ = 0.f;
#pragma unroll
  for (int ww = 0; ww < 4; ww++) {
    ai_ += red[ww][b][j];
    af_ += red[ww][b][16 + j];
    ao_ += red[ww][b][32 + j];
    ag_ += red[ww][b][48 + j];
  }
  ai_ += bp[pcol + j]; af_ += bp[pcol + 16 + j]; ao_ += bp[pcol + 32 + j]; ag_ += bp[pcol + 48 + j];

  float ig = 1.f / (1.f + __expf(-ai_));
  float fg = 1.f / (1.f + __expf(-af_));
  float og = 1.f / (1.f + __expf(-ao_));
  float gg = tanhf(ag_);
  int hidx = (b0 + b) * 1024 + cg * 16 + j;
  float cn = cst[hidx] * fg + ig * gg;
  cst[hidx] = cn;
  float h = og * tanhf(cn);
  out[(size_t)t * 65536 + hidx] = h;
  hnext[hidx] = f2bf(h);
  if (t == SEQ - 1) out[(size_t)SEQ * 65536 + hidx] = h;
}

// ---------------- host ----------------

extern "C" void kernel_launch(void* const* d_in, const int* in_sizes, int n_in,
                              void* d_out, int out_size, void* d_ws, size_t ws_size,
                              hipStream_t stream) {
  const float* X    = (const float*)d_in[0];
  const float* W    = (const float*)d_in[1];
  const float* bvec = (const float*)d_in[2];
  float* out = (float*)d_out;
  char* ws = (char*)d_ws;

  size_t off = 0;
  auto alloc = [&](size_t bytes) -> char* {
    char* p = ws + off;
    off += (bytes + 255) & ~(size_t)255;
    return p;
  };
  ushort* Xb    = (ushort*)alloc((size_t)SEQ * BATCH * NIN * 2);
  ushort* Wxb   = (ushort*)alloc((size_t)NG * NIN * 2);
  ushort* Whb   = (ushort*)alloc((size_t)NG * NHID * 2);
  float*  bp    = (float*)alloc((size_t)NG * 4);
  ushort* hb0   = (ushort*)alloc((size_t)BATCH * NHID * 2);
  ushort* hb1   = (ushort*)alloc((size_t)BATCH * NHID * 2);
  float*  cst   = (float*)alloc((size_t)BATCH * NHID * 4);
  uint32_t* flg = (uint32_t*)alloc(256 * 4);
  size_t base_need = off;

  if (ws_size < base_need) return;

  // largest chunk length TC (steps) whose f32 Ax chunk fits the remaining ws
  size_t avail = ws_size - base_need;
  int TC = 0;
  for (int tc = 512; tc >= 16; tc >>= 1) {
    if ((size_t)tc * 64 * NG * 4 <= avail) { TC = tc; break; }
  }
  float* Axc = (float*)(ws + base_need);  // base_need is 256B-aligned

  k_convert_x<<<(SEQ * BATCH * NIN / 4 + 255) / 256, 256, 0, stream>>>(X, Xb, SEQ * BATCH * NIN / 4);
  k_convert_w<<<NG, 256, 0, stream>>>(W, bvec, Wxb, Whb, bp);
  k_zero<<<BATCH * NHID / 256, 256, 0, stream>>>(hb0, hb1, cst, flg);

  if (TC > 0) {
    for (int c = 0; c < SEQ / TC; ++c) {
      k_gemm1<<<dim3(TC * 64 / 128, NG / 128), 256, 0, stream>>>(
          Xb + (size_t)c * TC * 64 * 1024, Wxb, bp, Axc);
      k_persist<<<256, 256, 0, stream>>>(Whb, Axc, hb0, hb1, out, flg, cst, c * TC, TC);
    }
  } else {
    for (int t = 0; t < SEQ; t++) {
      const ushort* hp = (t & 1) ? hb1 : hb0;
      ushort*       hn = (t & 1) ? hb0 : hb1;
      k_step<<<256, 256, 0, stream>>>(t, Xb, Wxb, Whb, bp, hp, hn, cst, out);
    }
  }
}

// Round 5
// 2927.481 us; speedup vs baseline: 2.0641x; 1.0631x over previous
//
#include <hip/hip_runtime.h>
#include <hip/hip_bf16.h>
#include <stdint.h>
#include <stddef.h>

#define SEQ   512
#define BATCH 64
#define NIN   1024
#define NHID  1024
#define NG    4096   // 4*NHID

typedef __attribute__((ext_vector_type(8))) short bf16x8;
typedef __attribute__((ext_vector_type(4))) float f32x4;
typedef __attribute__((ext_vector_type(4))) uint32_t u32x4;

static __device__ __forceinline__ ushort f2bf(float f) {
  uint32_t u = __builtin_bit_cast(uint32_t, f);
  uint32_t lsb = (u >> 16) & 1u;
  u += 0x7fffu + lsb;           // round-to-nearest-even
  return (ushort)(u >> 16);
}

static __device__ __forceinline__ f32x4 mfma_bf16(bf16x8 a, bf16x8 b, f32x4 c) {
  return __builtin_amdgcn_mfma_f32_16x16x32_bf16(a, b, c, 0, 0, 0);
}

static __device__ __forceinline__ void lds_load16(const ushort* g, ushort* l) {
  __builtin_amdgcn_global_load_lds(
      (const __attribute__((address_space(1))) void*)g,
      (__attribute__((address_space(3))) void*)l, 16, 0, 0);
}

// L3-coherent (cross-XCD) primitives: sc0 sc1 bypasses L1+L2 both ways.
static __device__ __forceinline__ void st_dword_l3(uint32_t* p, uint32_t v) {
  asm volatile("global_store_dword %0, %1, off sc0 sc1" :: "v"(p), "v"(v) : "memory");
}
static __device__ __forceinline__ u32x4 ld_x4_l3(const uint32_t* p) {
  u32x4 v;
  asm volatile("global_load_dwordx4 %0, %1, off sc0 sc1" : "=v"(v) : "v"(p) : "memory");
  return v;
}

// fast transcendentals (v_exp_f32 + v_rcp_f32); rel err ~1e-6 << bf16 quantum
static __device__ __forceinline__ float sigm_f(float x) {
  return __builtin_amdgcn_rcpf(1.f + __expf(-x));
}
static __device__ __forceinline__ float tanh_f(float x) {
  return 1.f - 2.f * __builtin_amdgcn_rcpf(__expf(2.f * x) + 1.f);
}

// ---------------- converts ----------------

__global__ __launch_bounds__(256) void k_convert_x(const float* __restrict__ X,
                                                   ushort* __restrict__ Xb, int n4) {
  int i = blockIdx.x * 256 + threadIdx.x;
  if (i < n4) {
    float4 v = ((const float4*)X)[i];
    ushort4 o;
    o.x = f2bf(v.x); o.y = f2bf(v.y); o.z = f2bf(v.z); o.w = f2bf(v.w);
    ((ushort4*)Xb)[i] = o;
  }
}

// permuted row order: p = cg*64 + g*16 + j  <->  r = g*1024 + cg*16 + j
__global__ __launch_bounds__(256) void k_convert_w(const float* __restrict__ W,
                                                   const float* __restrict__ bvec,
                                                   ushort* __restrict__ Wxb,
                                                   ushort* __restrict__ Whb,
                                                   float* __restrict__ bp) {
  int p = blockIdx.x;
  int cg = p >> 6, g = (p >> 4) & 3, j = p & 15;
  int r = g * 1024 + cg * 16 + j;
  const float* src = W + (size_t)r * 2048;
  for (int k4 = threadIdx.x; k4 < 512; k4 += 256) {
    float4 v = ((const float4*)src)[k4];
    ushort4 o;
    o.x = f2bf(v.x); o.y = f2bf(v.y); o.z = f2bf(v.z); o.w = f2bf(v.w);
    if (k4 < 256) ((ushort4*)(Wxb + (size_t)p * 1024))[k4] = o;
    else          ((ushort4*)(Whb + (size_t)p * 1024))[k4 - 256] = o;
  }
  if (threadIdx.x == 0) bp[p] = bvec[r];
}

// zero tagged h buffers (tag 0 == expected tag at t=0), fallback h, c-state
__global__ __launch_bounds__(256) void k_zero(uint32_t* __restrict__ ht0,
                                              uint32_t* __restrict__ ht1,
                                              ushort* __restrict__ hb0,
                                              ushort* __restrict__ hb1,
                                              float* __restrict__ cst) {
  int i = blockIdx.x * 256 + threadIdx.x;  // 65536 total
  st_dword_l3(ht0 + i, 0u);
  st_dword_l3(ht1 + i, 0u);
  hb0[i] = 0; hb1[i] = 0;
  cst[i] = 0.f;
}

// ---------------- GEMM1 chunk: Axc[m][p] = sum_k Xbc[m][k]*Wxb[p][k] + bp[p] ----------------
// 128x128 tile, BK=32, 4 waves (2x2 of 64x64). M = TC*64 rows of the Xb chunk.

__global__ __launch_bounds__(256) void k_gemm1(const ushort* __restrict__ Xbc,
                                               const ushort* __restrict__ Wxb,
                                               const float* __restrict__ bp,
                                               float* __restrict__ Axc) {
  __shared__ ushort As[128 * 32];
  __shared__ ushort Bs[128 * 32];
  const int m0 = blockIdx.x * 128;
  const int n0 = blockIdx.y * 128;
  const int tid = threadIdx.x;
  const int w = tid >> 6, l = tid & 63;
  const int wr = w >> 1, wc = w & 1;
  const int lr = l >> 2;          // row within 16-row chunk
  const int lc = (l & 3) * 8;     // elem col within 32
  const int fr = l & 15, fk8 = (l >> 4) * 8, fq = l >> 4;

  f32x4 acc[4][4] = {};

  for (int kb = 0; kb < 1024; kb += 32) {
    lds_load16(Xbc + (size_t)(m0 + w * 16 + lr) * 1024 + kb + lc,       &As[w * 512]);
    lds_load16(Xbc + (size_t)(m0 + (w + 4) * 16 + lr) * 1024 + kb + lc, &As[(w + 4) * 512]);
    lds_load16(Wxb + (size_t)(n0 + w * 16 + lr) * 1024 + kb + lc,       &Bs[w * 512]);
    lds_load16(Wxb + (size_t)(n0 + (w + 4) * 16 + lr) * 1024 + kb + lc, &Bs[(w + 4) * 512]);
    __syncthreads();
    bf16x8 af[4], bfr[4];
#pragma unroll
    for (int i = 0; i < 4; i++) af[i]  = *(const bf16x8*)&As[(wr * 64 + i * 16 + fr) * 32 + fk8];
#pragma unroll
    for (int i = 0; i < 4; i++) bfr[i] = *(const bf16x8*)&Bs[(wc * 64 + i * 16 + fr) * 32 + fk8];
#pragma unroll
    for (int i = 0; i < 4; i++)
#pragma unroll
      for (int jj = 0; jj < 4; jj++)
        acc[i][jj] = mfma_bf16(af[i], bfr[jj], acc[i][jj]);
    __syncthreads();
  }

#pragma unroll
  for (int jj = 0; jj < 4; jj++) {
    int gc = n0 + wc * 64 + jj * 16 + fr;
    float bb = bp[gc];
#pragma unroll
    for (int i = 0; i < 4; i++) {
      int grb = m0 + wr * 64 + i * 16 + fq * 4;
#pragma unroll
      for (int jr = 0; jr < 4; jr++)
        Axc[(size_t)(grb + jr) * NG + gc] = acc[i][jj][jr] + bb;
    }
  }
}

// ---------------- persistent recurrence chunk ----------------
// grid 256 = 4 teams x 64 hidden-groups; 144KB LDS -> 1 block/CU, co-resident.
// h exchange: EPOCH-TAGGED dwords ((t+1)<<16 | bf16) through L3 (sc0 sc1).
// No flags, no producer drain: consumers poll the data itself. Two buffers
// ping-ponged on t-parity make overwrite provably ordered (buffer written at
// step t is rewritten at t+2, which requires every block to have finished its
// step-t+1 poll of that buffer) -- no timing assumptions (G16).

__global__ __launch_bounds__(256) void k_persist(const ushort* __restrict__ Whb,
                                                 const float* __restrict__ Axc,
                                                 uint32_t* __restrict__ ht0,
                                                 uint32_t* __restrict__ ht1,
                                                 float* __restrict__ out,
                                                 float* __restrict__ cst,
                                                 int t0, int TC) {
  __shared__ ushort Wsh[64 * 1024];      // 128 KB
  __shared__ float red[4][16][64];       // 16 KB

  const int bid = blockIdx.x;
  const int team = bid >> 6, hg = bid & 63;
  const int tid = threadIdx.x, w = tid >> 6, l = tid & 63;
  const int fr = l & 15, fq = l >> 4;
  const int xm = (fr & 7) << 3;          // per-lane LDS XOR mask (elem units)

  // ---- stage Wh slice into LDS (once per chunk), swizzled ----
  {
    const ushort* wsrc = Whb + (size_t)(hg * 64) * 1024;
    for (int it = 0; it < 32; ++it) {
      int idx = it * 256 + tid;          // 8192 chunks of 8 elems
      int row = idx >> 7, c8 = idx & 127;
      bf16x8 v = *(const bf16x8*)(wsrc + (size_t)row * 1024 + c8 * 8);
      int col = (c8 * 8) ^ ((row & 7) << 3);
      *(bf16x8*)&Wsh[row * 1024 + col] = v;
    }
  }

  const int eb = tid >> 4, ej = tid & 15;  // epilogue: batch-in-team, hcol-in-group
  const int hidx_self = (team * 16 + eb) * 1024 + hg * 16 + ej;
  float creg = cst[hidx_self];
  __syncthreads();

  // per-thread read base (row = team*16+fr, cols w*256 + fq*8 + ...)
  const size_t roff = (size_t)(team * 16 + fr) * 1024 + w * 256 + fq * 8;
  const uint32_t* aB0 = ht0 + roff;
  const uint32_t* aB1 = ht1 + roff;
  uint32_t* hw0 = ht0 + hidx_self;
  uint32_t* hw1 = ht1 + hidx_self;

  for (int tt = 0; tt < TC; ++tt) {
    const int t = t0 + tt;
    // consumer reads buf[(t+1)&1] expecting tag t; producer writes buf[t&1] tag t+1
    const uint32_t* aBt = (t & 1) ? aB0 : aB1;
    uint32_t*       hWt = (t & 1) ? hw1 : hw0;

    // ---- Ax prefetch (h-independent; overlaps the poll) ----
    const float* axp = Axc + ((size_t)tt * 64 + team * 16 + eb) * NG + hg * 64;
    float ax0 = axp[ej], ax1 = axp[16 + ej], ax2 = axp[32 + ej], ax3 = axp[48 + ej];

    // ---- poll tagged h: the poll IS the data load ----
    u32x4 hv[16];
    const uint32_t expHi = (uint32_t)t << 16;
    int guard = 0;
    while (true) {
#pragma unroll
      for (int ks = 0; ks < 8; ++ks) {
        hv[2 * ks]     = ld_x4_l3(aBt + ks * 32);
        hv[2 * ks + 1] = ld_x4_l3(aBt + ks * 32 + 4);
      }
      asm volatile("s_waitcnt vmcnt(0)" ::: "memory");
      __builtin_amdgcn_sched_barrier(0);
      uint32_t m = 0;
#pragma unroll
      for (int i = 0; i < 16; ++i) {
        m |= hv[i][0] ^ expHi; m |= hv[i][1] ^ expHi;
        m |= hv[i][2] ^ expHi; m |= hv[i][3] ^ expHi;
      }
      if (__all((int)((m >> 16) == 0))) break;   // all 64 tags == t
      if (++guard > (1 << 13)) break;            // bug guard: fail, don't hang
    }

    // ---- unpack (strip tags) + MFMA over this wave's K-quarter ----
    f32x4 acc[4] = {};
#pragma unroll
    for (int ks = 0; ks < 8; ++ks) {
      uint32_t d0 = (hv[2 * ks][1] << 16)     | (hv[2 * ks][0] & 0xffffu);
      uint32_t d1 = (hv[2 * ks][3] << 16)     | (hv[2 * ks][2] & 0xffffu);
      uint32_t d2 = (hv[2 * ks + 1][1] << 16) | (hv[2 * ks + 1][0] & 0xffffu);
      uint32_t d3 = (hv[2 * ks + 1][3] << 16) | (hv[2 * ks + 1][2] & 0xffffu);
      u32x4 packed = {d0, d1, d2, d3};
      bf16x8 a = __builtin_bit_cast(bf16x8, packed);
#pragma unroll
      for (int bj = 0; bj < 4; ++bj) {
        int row = bj * 16 + fr;
        int col = (w * 256 + ks * 32 + fq * 8) ^ xm;
        bf16x8 bv = *(const bf16x8*)&Wsh[row * 1024 + col];
        acc[bj] = mfma_bf16(a, bv, acc[bj]);
      }
    }

#pragma unroll
    for (int bj = 0; bj < 4; ++bj)
#pragma unroll
      for (int jr = 0; jr < 4; ++jr)
        red[w][fq * 4 + jr][bj * 16 + fr] = acc[bj][jr];
    __syncthreads();

    // ---- epilogue: one (batch, hcol) per thread ----
    float ai_ = 0.f, af_ = 0.f, ao_ = 0.f, ag_ = 0.f;
#pragma unroll
    for (int ww = 0; ww < 4; ++ww) {
      ai_ += red[ww][eb][ej];
      af_ += red[ww][eb][16 + ej];
      ao_ += red[ww][eb][32 + ej];
      ag_ += red[ww][eb][48 + ej];
    }
    ai_ += ax0; af_ += ax1; ao_ += ax2; ag_ += ax3;

    float ig = sigm_f(ai_);
    float fg = sigm_f(af_);
    float og = sigm_f(ao_);
    float gg = tanh_f(ag_);
    creg = creg * fg + ig * gg;
    float h = og * tanh_f(creg);

    // publish FIRST (tagged, fire-and-forget), then HBM out store
    st_dword_l3(hWt, ((uint32_t)(t + 1) << 16) | (uint32_t)f2bf(h));
    out[(size_t)t * 65536 + hidx_self] = h;
    if (t == SEQ - 1) out[(size_t)SEQ * 65536 + hidx_self] = h;

    __syncthreads();   // red[] reuse guard
  }

  cst[hidx_self] = creg;
}

// ---------------- fallback per-step kernel (ws too small for any Ax chunk) ----------------

__global__ __launch_bounds__(256) void k_step(int t,
                                              const ushort* __restrict__ Xb,
                                              const ushort* __restrict__ Wxb,
                                              const ushort* __restrict__ Whb,
                                              const float* __restrict__ bp,
                                              const ushort* __restrict__ hprev,
                                              ushort* __restrict__ hnext,
                                              float* __restrict__ cst,
                                              float* __restrict__ out) {
  __shared__ float red[4][16][64];
  const int bidx = blockIdx.x;
  const int cg = bidx & 63, mb = bidx >> 6;
  const int b0 = mb * 16, pcol = cg * 64;
  const int tid = threadIdx.x, w = tid >> 6, l = tid & 63;
  const int fr = l & 15, fk8 = (l >> 4) * 8, fq = l >> 4;

  f32x4 acc[4] = {};

  const ushort* aSrc;
  const ushort* bMat;
  int kbase;
  if (w < 2) { aSrc = Xb + (size_t)(t * 64 + b0 + fr) * 1024 + w * 512 + fk8; bMat = Wxb; kbase = w * 512; }
  else       { aSrc = hprev + (size_t)(b0 + fr) * 1024 + (w - 2) * 512 + fk8; bMat = Whb; kbase = (w - 2) * 512; }
  const ushort* bRow = bMat + (size_t)(pcol + fr) * 1024 + kbase + fk8;

#pragma unroll
  for (int ks = 0; ks < 16; ks++) {
    int kk = ks * 32;
    bf16x8 a = *(const bf16x8*)(aSrc + kk);
#pragma unroll
    for (int bj = 0; bj < 4; bj++) {
      bf16x8 bfv = *(const bf16x8*)(bRow + (size_t)bj * 16 * 1024 + kk);
      acc[bj] = mfma_bf16(a, bfv, acc[bj]);
    }
  }

#pragma unroll
  for (int bj = 0; bj < 4; bj++)
#pragma unroll
    for (int jr = 0; jr < 4; jr++)
      red[w][fq * 4 + jr][bj * 16 + fr] = acc[bj][jr];
  __syncthreads();

  const int b = tid >> 4, j = tid & 15;
  float ai_ = 0.f, af_ = 0.f, ao_ = 0.f, ag_ = 0.f;
#pragma unroll
  for (int ww = 0; ww < 4; ww++) {
    ai_ += red[ww][b][j];
    af_ += red[ww][b][16 + j];
    ao_ += red[ww][b][32 + j];
    ag_ += red[ww][b][48 + j];
  }
  ai_ += bp[pcol + j]; af_ += bp[pcol + 16 + j]; ao_ += bp[pcol + 32 + j]; ag_ += bp[pcol + 48 + j];

  float ig = sigm_f(ai_);
  float fg = sigm_f(af_);
  float og = sigm_f(ao_);
  float gg = tanh_f(ag_);
  int hidx = (b0 + b) * 1024 + cg * 16 + j;
  float cn = cst[hidx] * fg + ig * gg;
  cst[hidx] = cn;
  float h = og * tanh_f(cn);
  out[(size_t)t * 65536 + hidx] = h;
  hnext[hidx] = f2bf(h);
  if (t == SEQ - 1) out[(size_t)SEQ * 65536 + hidx] = h;
}

// ---------------- host ----------------

extern "C" void kernel_launch(void* const* d_in, const int* in_sizes, int n_in,
                              void* d_out, int out_size, void* d_ws, size_t ws_size,
                              hipStream_t stream) {
  const float* X    = (const float*)d_in[0];
  const float* W    = (const float*)d_in[1];
  const float* bvec = (const float*)d_in[2];
  float* out = (float*)d_out;
  char* ws = (char*)d_ws;

  size_t off = 0;
  auto alloc = [&](size_t bytes) -> char* {
    char* p = ws + off;
    off += (bytes + 255) & ~(size_t)255;
    return p;
  };
  ushort*   Xb  = (ushort*)alloc((size_t)SEQ * BATCH * NIN * 2);
  ushort*   Wxb = (ushort*)alloc((size_t)NG * NIN * 2);
  ushort*   Whb = (ushort*)alloc((size_t)NG * NHID * 2);
  float*    bp  = (float*)alloc((size_t)NG * 4);
  uint32_t* ht0 = (uint32_t*)alloc((size_t)BATCH * NHID * 4);
  uint32_t* ht1 = (uint32_t*)alloc((size_t)BATCH * NHID * 4);
  ushort*   hb0 = (ushort*)alloc((size_t)BATCH * NHID * 2);
  ushort*   hb1 = (ushort*)alloc((size_t)BATCH * NHID * 2);
  float*    cst = (float*)alloc((size_t)BATCH * NHID * 4);
  size_t base_need = off;

  if (ws_size < base_need) return;

  // largest chunk length TC (steps) whose f32 Ax chunk fits the remaining ws
  size_t avail = ws_size - base_need;
  int TC = 0;
  for (int tc = 512; tc >= 16; tc >>= 1) {
    if ((size_t)tc * 64 * NG * 4 <= avail) { TC = tc; break; }
  }
  float* Axc = (float*)(ws + base_need);  // base_need is 256B-aligned

  k_convert_x<<<(SEQ * BATCH * NIN / 4 + 255) / 256, 256, 0, stream>>>(X, Xb, SEQ * BATCH * NIN / 4);
  k_convert_w<<<NG, 256, 0, stream>>>(W, bvec, Wxb, Whb, bp);
  k_zero<<<BATCH * NHID / 256, 256, 0, stream>>>(ht0, ht1, hb0, hb1, cst);

  if (TC > 0) {
    for (int c = 0; c < SEQ / TC; ++c) {
      k_gemm1<<<dim3(TC * 64 / 128, NG / 128), 256, 0, stream>>>(
          Xb + (size_t)c * TC * 64 * 1024, Wxb, bp, Axc);
      k_persist<<<256, 256, 0, stream>>>(Whb, Axc, ht0, ht1, out, cst, c * TC, TC);
    }
  } else {
    for (int t = 0; t < SEQ; t++) {
      const ushort* hp = (t & 1) ? hb1 : hb0;
      ushort*       hn = (t & 1) ? hb0 : hb1;
      k_step<<<256, 256, 0, stream>>>(t, Xb, Wxb, Whb, bp, hp, hn, cst, out);
    }
  }
}